// Round 9
// baseline (178.352 us; speedup 1.0000x reference)
//
#include <hip/hip_runtime.h>
#include <hip/hip_bf16.h>

// MHA forward, all-bf16 MFMA pipeline (fp32 accum):
//  k1 convert: x,wq|wk|wv,wo fp32 -> bf16 (wqkv packed [3072][1024])
//  k2 gemm_qkv: xb @ wqkv^T (m97 2-barrier K-loop, single-buffer: dbuf
//      regresses occupancy -- k2 is LDS/VGPR-capped) -> qb (pre-scaled
//      log2e/8), kb, vtb[bh][64][2048]
//  k3 attn v2 (PROVEN BEST 48.6us): Tq=128, 8 waves (qg,kh), K/V dbuf
//      gload_lds, P via LDS, fixed-max softmax, 1 barrier/iter.
//      Falsified: v3 K-to-reg (75us latency), v4 K-reg pipelined (85us
//      spills), v5 softmax pipeline (53us), v6 32x32 in-reg P (54.6us
//      4-way frag conflicts).
//  k4 gemm_out v2: 128x64 tiles, grid 512 = 2 blocks/CU (grid-capped ->
//      dbuf is FREE here, unlike k2): attn-style dbuf 1-barrier K-loop,
//      prefetch issued before compute so stage(k+1) has the whole
//      compute(k) phase in flight before the barrier drain. LDS 24->48KB.

typedef unsigned short u16;
typedef unsigned int u32;
using short8 = __attribute__((ext_vector_type(8))) short;
using f32x4  = __attribute__((ext_vector_type(4))) float;

#define WS_XB    0u
#define WS_WQKV  8388608u
#define WS_WOB   14680064u
#define WS_QB    16777216u
#define WS_KB    25165824u
#define WS_VTB   33554432u
#define WS_OB    41943040u

__device__ __forceinline__ u16 f2bf(float f) {
  u32 u = __float_as_uint(f);
  u += 0x7fffu + ((u >> 16) & 1u);
  return (u16)(u >> 16);
}

__device__ __forceinline__ ushort4 pk4(f32x4 v) {
  ushort4 r; r.x = f2bf(v[0]); r.y = f2bf(v[1]); r.z = f2bf(v[2]); r.w = f2bf(v[3]);
  return r;
}

__device__ __forceinline__ u32 pkbf2(float lo, float hi) {
  union { __hip_bfloat162 b; u32 u; } c;
  c.b = __float22bfloat162_rn(make_float2(lo, hi));
  return c.u;
}

__device__ __forceinline__ void gload16(const void* g, void* l) {
  __builtin_amdgcn_global_load_lds(
      (const __attribute__((address_space(1))) u32*)g,
      (__attribute__((address_space(3))) u32*)l, 16, 0, 0);
}

#define KSCALE 0.18033688011112042f  // log2(e)/sqrt(64)

// ---------------- k1: fp32 -> bf16 ----------------
__global__ void convert_k(const float* __restrict__ x, const float* __restrict__ wq,
                          const float* __restrict__ wk, const float* __restrict__ wv,
                          const float* __restrict__ wo,
                          u16* __restrict__ xb, u16* __restrict__ wqkv, u16* __restrict__ wob) {
  size_t g = ((size_t)blockIdx.x * 256 + threadIdx.x) * 4;
  const float* s; u16* d;
  if (g < 4194304u)      { s = x  + g;            d = xb   + g; }
  else if (g < 5242880u) { s = wq + (g - 4194304u); d = wqkv + (g - 4194304u); }
  else if (g < 6291456u) { s = wk + (g - 5242880u); d = wqkv + 1048576u + (g - 5242880u); }
  else if (g < 7340032u) { s = wv + (g - 6291456u); d = wqkv + 2097152u + (g - 6291456u); }
  else                   { s = wo + (g - 7340032u); d = wob  + (g - 7340032u); }
  float4 v = *(const float4*)s;
  f32x4 vv = {v.x, v.y, v.z, v.w};
  *(ushort4*)d = pk4(vv);
}

// ---------------- k2: QKV projection (single-buffer, m97 structure) ----------------
__global__ void gemm_qkv(const u16* __restrict__ A, const u16* __restrict__ Bt,
                         u16* __restrict__ qb, u16* __restrict__ kb, u16* __restrict__ vtb) {
  __shared__ __align__(16) u16 As[128 * 64];
  __shared__ __align__(16) u16 Bs[128 * 64];
  const int tid  = threadIdx.x;
  const int wave = tid >> 6, lane = tid & 63;
  const int c16  = lane & 15, quad = lane >> 4;
  const int tile_m = blockIdx.x * 128;
  const int tile_n = blockIdx.y * 128;
  const int wm = (wave >> 1) * 64, wn = (wave & 1) * 64;
  const int srow = wave * 32 + (lane >> 3);
  const int sc   = lane & 7;
  const int which = blockIdx.y >> 3;       // 0:Q 1:K 2:V
  const bool swp  = (which < 2);

  const u16* Pa = swp ? Bs : As;
  const u16* Pb = swp ? As : Bs;
  const int  ra = swp ? wn : wm;
  const int  rb = swp ? wm : wn;

  f32x4 acc[4][4] = {};

  for (int k0 = 0; k0 < 1024; k0 += 64) {
    __syncthreads();
#pragma unroll
    for (int j = 0; j < 4; ++j) {
      int row = srow + j * 8;
      int cp  = sc ^ (row & 7);
      gload16(A  + (size_t)(tile_m + row) * 1024 + k0 + cp * 8, As + row * 64 + sc * 8);
      gload16(Bt + (size_t)(tile_n + row) * 1024 + k0 + cp * 8, Bs + row * 64 + sc * 8);
    }
    __syncthreads();
#pragma unroll
    for (int kc = 0; kc < 2; ++kc) {
      const int ch = ((kc * 4 + quad) ^ (c16 & 7)) * 8;
      short8 fa[4], fb[4];
#pragma unroll
      for (int i = 0; i < 4; ++i)
        fa[i] = *(const short8*)(Pa + (ra + i * 16 + c16) * 64 + ch);
#pragma unroll
      for (int j = 0; j < 4; ++j)
        fb[j] = *(const short8*)(Pb + (rb + j * 16 + c16) * 64 + ch);
#pragma unroll
      for (int i = 0; i < 4; ++i)
#pragma unroll
        for (int j = 0; j < 4; ++j)
          acc[i][j] = __builtin_amdgcn_mfma_f32_16x16x32_bf16(fa[i], fb[j], acc[i][j], 0, 0, 0);
    }
  }

  if (which == 2) {
#pragma unroll
    for (int i = 0; i < 4; ++i) {
      int m0 = tile_m + wm + i * 16 + quad * 4;
      int bb = m0 >> 11, ss0 = m0 & 2047;
#pragma unroll
      for (int j = 0; j < 4; ++j) {
        int f = (tile_n & 1023) + wn + j * 16 + c16;
        int h = f >> 6, d = f & 63;
        *(ushort4*)(vtb + ((size_t)(bb * 16 + h) * 64 + d) * 2048 + ss0) = pk4(acc[i][j]);
      }
    }
  } else {
    u16* dstb = which ? kb : qb;
#pragma unroll
    for (int i = 0; i < 4; ++i) {
      int full = (tile_n & 1023) + wn + i * 16 + quad * 4;
      int h = full >> 6, d0 = full & 63;
#pragma unroll
      for (int j = 0; j < 4; ++j) {
        int t = tile_m + wm + j * 16 + c16;
        int bb = t >> 11, ss = t & 2047;
        f32x4 v = acc[i][j];
        if (which == 0) { v[0] *= KSCALE; v[1] *= KSCALE; v[2] *= KSCALE; v[3] *= KSCALE; }
        *(ushort4*)(dstb + ((size_t)(bb * 16 + h) * 2048 + ss) * 64 + d0) = pk4(v);
      }
    }
  }
}

// ---------------- k3: flash attention, 8 waves = 4 q-groups x 2 key-halves ----------------
__global__ __launch_bounds__(512) void attn_k(const u16* __restrict__ qb, const u16* __restrict__ kb,
                                              const u16* __restrict__ vtb, const int* __restrict__ mask,
                                              u16* __restrict__ ob) {
  // smem carve: Ks[2][4096]u16 @0, Vs[2][4096]u16 @16384, Ps[128][64]u16 @32768,
  //             mask2[1024]u32 @49152. Epilogue reuses [0,34304) as f32 reduce buf.
  __shared__ __align__(16) char smem[53248];
  u16* const KsB   = (u16*)smem;
  u16* const VsB   = (u16*)(smem + 16384);
  u16* const Ps    = (u16*)(smem + 32768);
  u32* const mask2 = (u32*)(smem + 49152);

  const int tid  = threadIdx.x;
  const int wave = tid >> 6, lane = tid & 63;
  const int c16  = lane & 15, g4 = lane >> 4;
  const int qg   = wave >> 1;        // q 32-block within tile (0..3)
  const int kh   = wave & 1;         // key half of the 64-key tile

  // XCD-bijective remap: flat = x + 16*y; xcd gets a contiguous 64-block chunk
  // = 4 bh x 16 q-blocks, so each bh's 512KB K/V is read within one L2.
  const int f    = blockIdx.x + 16 * blockIdx.y;
  const int i64  = f >> 3;
  const int bh   = (f & 7) * 4 + (i64 >> 4);
  const int q0   = (i64 & 15) * 128;
  const int bidx = bh >> 4, h = bh & 15;

  { // packed keep-masks for all 2048 keys (4 keys/thread)
    int4 m0 = *(const int4*)(mask + bidx * 2048 + tid * 4);
    uint2 dd;
    dd.x = (m0.x ? 0u : 0xFFFFu) | (m0.y ? 0u : 0xFFFF0000u);
    dd.y = (m0.z ? 0u : 0xFFFFu) | (m0.w ? 0u : 0xFFFF0000u);
    *(uint2*)(mask2 + tid * 2) = dd;
  }

  // Q fragments straight from global into registers (both kh waves of a qg
  // load the same rows -- duplicated, cheap)
  const u16* qg_ = qb + ((size_t)bh * 2048 + q0 + qg * 32) * 64;
  short8 qf[2][2];
#pragma unroll
  for (int kc = 0; kc < 2; ++kc)
#pragma unroll
    for (int nj = 0; nj < 2; ++nj)
      qf[kc][nj] = *(const short8*)(qg_ + (nj * 16 + c16) * 64 + kc * 32 + g4 * 8);

  const u16* kg = kb  + (size_t)bh * 2048 * 64;
  const u16* vg = vtb + (size_t)bh * 64 * 2048;
  { // stage K/V tile 0 into buffer 0: 512 threads, one 16B chunk each
    int r  = tid >> 3;
    int cp = (tid & 7) ^ (r & 7);
    gload16(kg + (size_t)r * 64 + cp * 8,   KsB + tid * 8);
    gload16(vg + (size_t)r * 2048 + cp * 8, VsB + tid * 8);
  }
  __syncthreads();

  short8 ones;
#pragma unroll
  for (int i = 0; i < 8; ++i) ones[i] = (short)0x3F80;   // bf16 1.0

  f32x4 O[2][4] = {};   // partial over this wave's key half
  f32x4 L[2] = {};

#pragma unroll 2
  for (int kt = 0; kt < 32; ++kt) {
    if (kt) __syncthreads();   // drains tile-kt loads + frees other buffer
    if (kt + 1 < 32) {
      const int nb = (kt + 1) & 1;
      int r  = tid >> 3;
      int cp = (tid & 7) ^ (r & 7);
      gload16(kg + (size_t)((kt + 1) * 64 + r) * 64 + cp * 8, KsB + nb * 4096 + tid * 8);
      gload16(vg + (size_t)r * 2048 + (kt + 1) * 64 + cp * 8, VsB + nb * 4096 + tid * 8);
    }
    const u16* ksb = KsB + (kt & 1) * 4096;
    const u16* vsb = VsB + (kt & 1) * 4096;

    // S^T[key 32 (this wave's half)][q 32]
    f32x4 S[2][2] = {};
    __builtin_amdgcn_s_setprio(1);
#pragma unroll
    for (int kc = 0; kc < 2; ++kc) {
      const int ch = ((kc * 4 + g4) ^ (c16 & 7)) * 8;
      short8 a[2];
#pragma unroll
      for (int mi = 0; mi < 2; ++mi)
        a[mi] = *(const short8*)(ksb + (kh * 32 + mi * 16 + c16) * 64 + ch);
#pragma unroll
      for (int mi = 0; mi < 2; ++mi)
#pragma unroll
        for (int nj = 0; nj < 2; ++nj)
          S[mi][nj] = __builtin_amdgcn_mfma_f32_16x16x32_bf16(a[mi], qf[kc][nj], S[mi][nj], 0, 0, 0);
    }
    __builtin_amdgcn_s_setprio(0);

    // keep-masks: reg r key = kh*32 + mi*16 + g4*4 + r
    uint2 mk[2];
#pragma unroll
    for (int mi = 0; mi < 2; ++mi)
      mk[mi] = *(const uint2*)(mask2 + kt * 32 + kh * 16 + mi * 8 + g4 * 2);

    // fixed-max softmax: P = exp2(S) & keep, packed to bf16, P -> LDS
    // (column half kh of Ps is wave-private: no barrier)
#pragma unroll
    for (int nj = 0; nj < 2; ++nj) {
      const int q = qg * 32 + nj * 16 + c16;
#pragma unroll
      for (int mi = 0; mi < 2; ++mi) {
        float p0 = __builtin_amdgcn_exp2f(S[mi][nj][0]);
        float p1 = __builtin_amdgcn_exp2f(S[mi][nj][1]);
        float p2 = __builtin_amdgcn_exp2f(S[mi][nj][2]);
        float p3 = __builtin_amdgcn_exp2f(S[mi][nj][3]);
        u32 lo = pkbf2(p0, p1) & mk[mi].x;
        u32 hi = pkbf2(p2, p3) & mk[mi].y;
        uint2 pkd; pkd.x = lo; pkd.y = hi;
        const int c = kh * 4 + mi * 2 + (g4 >> 1);
        *(uint2*)(Ps + q * 64 + ((c ^ (c16 & 7)) * 8 + (g4 & 1) * 4)) = pkd;
      }
    }

    // O[q 32][d 64] += P*V over this wave's 32 keys; L[q] += P*1
    {
      const int ch = ((kh * 4 + g4) ^ (c16 & 7)) * 8;
      short8 a2[2], b2[4];
#pragma unroll
      for (int mi = 0; mi < 2; ++mi)
        a2[mi] = *(const short8*)(Ps + (qg * 32 + mi * 16 + c16) * 64 + ch);
#pragma unroll
      for (int nd = 0; nd < 4; ++nd)
        b2[nd] = *(const short8*)(vsb + (nd * 16 + c16) * 64 + ch);
      __builtin_amdgcn_s_setprio(1);
#pragma unroll
      for (int mi = 0; mi < 2; ++mi) {
#pragma unroll
        for (int nd = 0; nd < 4; ++nd)
          O[mi][nd] = __builtin_amdgcn_mfma_f32_16x16x32_bf16(a2[mi], b2[nd], O[mi][nd], 0, 0, 0);
        L[mi] = __builtin_amdgcn_mfma_f32_16x16x32_bf16(a2[mi], ones, L[mi], 0, 0, 0);
      }
      __builtin_amdgcn_s_setprio(0);
    }
  }

  // epilogue: merge the two key-half partials (fixed-max => pure addition),
  // then O/L. Reduce buffer overlays the dead K/V/P LDS.
  __syncthreads();
  float* const redO = (float*)smem;            // [128][66] (+2 pad: 4-row bank spread)
  float* const redL = (float*)(smem + 33792);  // [128]
  if (kh) {
#pragma unroll
    for (int mi = 0; mi < 2; ++mi)
#pragma unroll
      for (int r = 0; r < 4; ++r) {
        int row = qg * 32 + mi * 16 + g4 * 4 + r;
#pragma unroll
        for (int nd = 0; nd < 4; ++nd)
          redO[row * 66 + nd * 16 + c16] = O[mi][nd][r];
        if (c16 == 0) redL[row] = L[mi][r];
      }
  }
  __syncthreads();
  if (!kh) {
    u16* og = ob + ((size_t)(bidx * 2048 + q0 + qg * 32)) * 1024 + h * 64;
#pragma unroll
    for (int mi = 0; mi < 2; ++mi)
#pragma unroll
      for (int r = 0; r < 4; ++r) {
        int row  = qg * 32 + mi * 16 + g4 * 4 + r;
        int qrow = mi * 16 + g4 * 4 + r;
        float linv = 1.f / (L[mi][r] + redL[row]);
#pragma unroll
        for (int nd = 0; nd < 4; ++nd) {
          float o = O[mi][nd][r] + redO[row * 66 + nd * 16 + c16];
          og[(size_t)qrow * 1024 + nd * 16 + c16] = f2bf(o * linv);
        }
      }
  }
}

// ---------------- k4: output projection v2 -- dbuf 1-barrier prefetch loop ----------------
__global__ __launch_bounds__(256) void gemm_out(const u16* __restrict__ A, const u16* __restrict__ Bt,
                         float* __restrict__ out) {
  __shared__ __align__(16) u16 As[2][128 * 64];
  __shared__ __align__(16) u16 Bs[2][64 * 64];
  const int tid  = threadIdx.x;
  const int wave = tid >> 6, lane = tid & 63;
  const int c16  = lane & 15, quad = lane >> 4;
  const int tile_m = blockIdx.x * 128;
  const int tile_n = blockIdx.y * 64;
  const int wm = wave * 32;
  const int sc   = lane & 7;

  f32x4 acc[4][2] = {};   // [feature blocks][token blocks]

  { // prologue: stage k-tile 0 into buffer 0
#pragma unroll
    for (int j = 0; j < 4; ++j) {
      int row = (tid >> 3) + j * 32;
      int cp  = sc ^ (row & 7);
      gload16(A + (size_t)(tile_m + row) * 1024 + cp * 8, &As[0][row * 64 + sc * 8]);
    }
#pragma unroll
    for (int j = 0; j < 2; ++j) {
      int row = (tid >> 3) + j * 32;
      int cp  = sc ^ (row & 7);
      gload16(Bt + (size_t)(tile_n + row) * 1024 + cp * 8, &Bs[0][row * 64 + sc * 8]);
    }
  }

  for (int kk = 0; kk < 16; ++kk) {
    __syncthreads();             // drains stage(kk); all waves done with buf kk^1
    if (kk + 1 < 16) {           // prefetch k-tile kk+1 -- has full compute(kk) in flight
      const int nb = (kk + 1) & 1;
      const int k0 = (kk + 1) * 64;
#pragma unroll
      for (int j = 0; j < 4; ++j) {
        int row = (tid >> 3) + j * 32;
        int cp  = sc ^ (row & 7);
        gload16(A + (size_t)(tile_m + row) * 1024 + k0 + cp * 8, &As[nb][row * 64 + sc * 8]);
      }
#pragma unroll
      for (int j = 0; j < 2; ++j) {
        int row = (tid >> 3) + j * 32;
        int cp  = sc ^ (row & 7);
        gload16(Bt + (size_t)(tile_n + row) * 1024 + k0 + cp * 8, &Bs[nb][row * 64 + sc * 8]);
      }
    }
    const u16* asb = As[kk & 1];
    const u16* bsb = Bs[kk & 1];
#pragma unroll
    for (int kc = 0; kc < 2; ++kc) {
      const int ch = ((kc * 4 + quad) ^ (c16 & 7)) * 8;
      short8 fa[4], fb[2];
#pragma unroll
      for (int i = 0; i < 4; ++i)
        fa[i] = *(const short8*)(bsb + (i * 16 + c16) * 64 + ch);       // features
#pragma unroll
      for (int j = 0; j < 2; ++j)
        fb[j] = *(const short8*)(asb + (wm + j * 16 + c16) * 64 + ch);  // tokens
#pragma unroll
      for (int i = 0; i < 4; ++i)
#pragma unroll
        for (int j = 0; j < 2; ++j)
          acc[i][j] = __builtin_amdgcn_mfma_f32_16x16x32_bf16(fa[i], fb[j], acc[i][j], 0, 0, 0);
    }
  }
#pragma unroll
  for (int i = 0; i < 4; ++i) {
    int f0 = tile_n + i * 16 + quad * 4;
#pragma unroll
    for (int j = 0; j < 2; ++j) {
      int t = tile_m + wm + j * 16 + c16;
      *(f32x4*)(out + (size_t)t * 1024 + f0) = acc[i][j];
    }
  }
}

extern "C" void kernel_launch(void* const* d_in, const int* in_sizes, int n_in,
                              void* d_out, int out_size, void* d_ws, size_t ws_size,
                              hipStream_t stream) {
  (void)in_sizes; (void)n_in; (void)out_size; (void)ws_size;
  const float* x    = (const float*)d_in[0];
  const int*   mask = (const int*)d_in[1];
  const float* wq   = (const float*)d_in[2];
  const float* wk   = (const float*)d_in[3];
  const float* wv   = (const float*)d_in[4];
  const float* wo   = (const float*)d_in[5];
  float* out = (float*)d_out;
  char*  ws  = (char*)d_ws;

  u16* xb   = (u16*)(ws + WS_XB);
  u16* wqkv = (u16*)(ws + WS_WQKV);
  u16* wob  = (u16*)(ws + WS_WOB);
  u16* qbuf = (u16*)(ws + WS_QB);
  u16* kbuf = (u16*)(ws + WS_KB);
  u16* vtb  = (u16*)(ws + WS_VTB);
  u16* obuf = (u16*)(ws + WS_OB);

  convert_k<<<8192, 256, 0, stream>>>(x, wq, wk, wv, wo, xb, wqkv, wob);
  gemm_qkv<<<dim3(32, 24), 256, 0, stream>>>(xb, wqkv, qbuf, kbuf, vtb);
  attn_k<<<dim3(16, 32), 512, 0, stream>>>(qbuf, kbuf, vtb, mask, obuf);
  gemm_out<<<dim3(32, 16), 256, 0, stream>>>(obuf, wob, out);
}

// Round 10
// 177.776 us; speedup vs baseline: 1.0032x; 1.0032x over previous
//
#include <hip/hip_runtime.h>
#include <hip/hip_bf16.h>

// MHA forward, all-bf16 MFMA pipeline (fp32 accum):
//  k1 convert: x,wq|wk|wv,wo fp32 -> bf16, grid-stride 2048 blocks
//  k2 gemm_qkv: xb @ wqkv^T (m97 2-barrier K-loop, single-buffer) ->
//      qb (pre-scaled log2e/8), kb, vtb[bh][64][2048]. V epilogue now
//      routes through the dead As/Bs LDS (32KB, [feat][tok]) and stores
//      coalesced 256B runs -- the old path was 8B stores at 4KB stride
//      (worst scatter in the pipeline, 8MB of partial-line writes).
//  k3 attn v2 (PROVEN BEST 48.6us): Tq=128, 8 waves (qg,kh), K/V dbuf
//      gload_lds, P via LDS, fixed-max softmax, 1 barrier/iter.
//      Falsified: v3 K-to-reg (75us latency), v4 K-reg pipelined (85us
//      spills), v5 softmax pipeline (53us), v6 32x32 in-reg P (54.6us
//      4-way frag conflicts). k4-dbuf also neutral (r9).
//  k4 gemm_out: 128x64 tiles, single-buffer 2-barrier loop (r8 config),
//      grid 512 = 2 blocks/CU, swapped epilogue -> float4 stores

typedef unsigned short u16;
typedef unsigned int u32;
using short8 = __attribute__((ext_vector_type(8))) short;
using f32x4  = __attribute__((ext_vector_type(4))) float;

#define WS_XB    0u
#define WS_WQKV  8388608u
#define WS_WOB   14680064u
#define WS_QB    16777216u
#define WS_KB    25165824u
#define WS_VTB   33554432u
#define WS_OB    41943040u

__device__ __forceinline__ u16 f2bf(float f) {
  u32 u = __float_as_uint(f);
  u += 0x7fffu + ((u >> 16) & 1u);
  return (u16)(u >> 16);
}

__device__ __forceinline__ ushort4 pk4(f32x4 v) {
  ushort4 r; r.x = f2bf(v[0]); r.y = f2bf(v[1]); r.z = f2bf(v[2]); r.w = f2bf(v[3]);
  return r;
}

__device__ __forceinline__ u32 pkbf2(float lo, float hi) {
  union { __hip_bfloat162 b; u32 u; } c;
  c.b = __float22bfloat162_rn(make_float2(lo, hi));
  return c.u;
}

__device__ __forceinline__ void gload16(const void* g, void* l) {
  __builtin_amdgcn_global_load_lds(
      (const __attribute__((address_space(1))) u32*)g,
      (__attribute__((address_space(3))) u32*)l, 16, 0, 0);
}

#define KSCALE 0.18033688011112042f  // log2(e)/sqrt(64)

// ---------------- k1: fp32 -> bf16 (grid-stride) ----------------
__global__ void convert_k(const float* __restrict__ x, const float* __restrict__ wq,
                          const float* __restrict__ wk, const float* __restrict__ wv,
                          const float* __restrict__ wo,
                          u16* __restrict__ xb, u16* __restrict__ wqkv, u16* __restrict__ wob) {
  for (size_t g = ((size_t)blockIdx.x * 256 + threadIdx.x) * 4; g < 8388608u;
       g += 2097152u) {   // 2048 blocks * 256 thr * 4 elems
    const float* s; u16* d;
    if (g < 4194304u)      { s = x  + g;            d = xb   + g; }
    else if (g < 5242880u) { s = wq + (g - 4194304u); d = wqkv + (g - 4194304u); }
    else if (g < 6291456u) { s = wk + (g - 5242880u); d = wqkv + 1048576u + (g - 5242880u); }
    else if (g < 7340032u) { s = wv + (g - 6291456u); d = wqkv + 2097152u + (g - 6291456u); }
    else                   { s = wo + (g - 7340032u); d = wob  + (g - 7340032u); }
    float4 v = *(const float4*)s;
    f32x4 vv = {v.x, v.y, v.z, v.w};
    *(ushort4*)d = pk4(vv);
  }
}

// ---------------- k2: QKV projection (single-buffer, m97 structure) ----------------
__global__ void gemm_qkv(const u16* __restrict__ A, const u16* __restrict__ Bt,
                         u16* __restrict__ qb, u16* __restrict__ kb, u16* __restrict__ vtb) {
  __shared__ __align__(16) u16 smem2[16384];   // As @0 (8K u16), Bs @8192; V-epilogue reuses all 32KB
  u16* const As = smem2;
  u16* const Bs = smem2 + 8192;
  const int tid  = threadIdx.x;
  const int wave = tid >> 6, lane = tid & 63;
  const int c16  = lane & 15, quad = lane >> 4;
  const int tile_m = blockIdx.x * 128;
  const int tile_n = blockIdx.y * 128;
  const int wm = (wave >> 1) * 64, wn = (wave & 1) * 64;
  const int srow = wave * 32 + (lane >> 3);
  const int sc   = lane & 7;
  const int which = blockIdx.y >> 3;       // 0:Q 1:K 2:V
  const bool swp  = (which < 2);

  const u16* Pa = swp ? Bs : As;
  const u16* Pb = swp ? As : Bs;
  const int  ra = swp ? wn : wm;
  const int  rb = swp ? wm : wn;

  f32x4 acc[4][4] = {};

  for (int k0 = 0; k0 < 1024; k0 += 64) {
    __syncthreads();
#pragma unroll
    for (int j = 0; j < 4; ++j) {
      int row = srow + j * 8;
      int cp  = sc ^ (row & 7);
      gload16(A  + (size_t)(tile_m + row) * 1024 + k0 + cp * 8, As + row * 64 + sc * 8);
      gload16(Bt + (size_t)(tile_n + row) * 1024 + k0 + cp * 8, Bs + row * 64 + sc * 8);
    }
    __syncthreads();
#pragma unroll
    for (int kc = 0; kc < 2; ++kc) {
      const int ch = ((kc * 4 + quad) ^ (c16 & 7)) * 8;
      short8 fa[4], fb[4];
#pragma unroll
      for (int i = 0; i < 4; ++i)
        fa[i] = *(const short8*)(Pa + (ra + i * 16 + c16) * 64 + ch);
#pragma unroll
      for (int j = 0; j < 4; ++j)
        fb[j] = *(const short8*)(Pb + (rb + j * 16 + c16) * 64 + ch);
#pragma unroll
      for (int i = 0; i < 4; ++i)
#pragma unroll
        for (int j = 0; j < 4; ++j)
          acc[i][j] = __builtin_amdgcn_mfma_f32_16x16x32_bf16(fa[i], fb[j], acc[i][j], 0, 0, 0);
    }
  }

  if (which == 2) {
    // V epilogue: stage tile to LDS [feat 128][tok 128], then coalesced stores.
    __syncthreads();               // all waves done reading As/Bs
#pragma unroll
    for (int i = 0; i < 4; ++i) {  // token dim
      const int tokL = wm + i * 16 + quad * 4;
#pragma unroll
      for (int j = 0; j < 4; ++j) {// feature dim
        const int featL = wn + j * 16 + c16;
        *(ushort4*)(smem2 + featL * 128 + tokL) = pk4(acc[i][j]);
      }
    }
    __syncthreads();
    const int fb0 = tile_n & 1023;
    const int bb  = tile_m >> 11, ssb = tile_m & 2047;
    u16* vbase = vtb + ((size_t)(bb * 16) * 64 + fb0) * 2048 + ssb;
#pragma unroll
    for (int ff = 0; ff < 16; ++ff) {
      const int feat = ff * 8 + (tid >> 5);
      const int tok  = (tid & 31) * 4;
      *(ushort4*)(vbase + (size_t)feat * 2048 + tok) =
          *(const ushort4*)(smem2 + feat * 128 + tok);
    }
  } else {
    u16* dstb = which ? kb : qb;
#pragma unroll
    for (int i = 0; i < 4; ++i) {
      int full = (tile_n & 1023) + wn + i * 16 + quad * 4;
      int h = full >> 6, d0 = full & 63;
#pragma unroll
      for (int j = 0; j < 4; ++j) {
        int t = tile_m + wm + j * 16 + c16;
        int bb = t >> 11, ss = t & 2047;
        f32x4 v = acc[i][j];
        if (which == 0) { v[0] *= KSCALE; v[1] *= KSCALE; v[2] *= KSCALE; v[3] *= KSCALE; }
        *(ushort4*)(dstb + ((size_t)(bb * 16 + h) * 2048 + ss) * 64 + d0) = pk4(v);
      }
    }
  }
}

// ---------------- k3: flash attention, 8 waves = 4 q-groups x 2 key-halves ----------------
__global__ __launch_bounds__(512) void attn_k(const u16* __restrict__ qb, const u16* __restrict__ kb,
                                              const u16* __restrict__ vtb, const int* __restrict__ mask,
                                              u16* __restrict__ ob) {
  // smem carve: Ks[2][4096]u16 @0, Vs[2][4096]u16 @16384, Ps[128][64]u16 @32768,
  //             mask2[1024]u32 @49152. Epilogue reuses [0,34304) as f32 reduce buf.
  __shared__ __align__(16) char smem[53248];
  u16* const KsB   = (u16*)smem;
  u16* const VsB   = (u16*)(smem + 16384);
  u16* const Ps    = (u16*)(smem + 32768);
  u32* const mask2 = (u32*)(smem + 49152);

  const int tid  = threadIdx.x;
  const int wave = tid >> 6, lane = tid & 63;
  const int c16  = lane & 15, g4 = lane >> 4;
  const int qg   = wave >> 1;        // q 32-block within tile (0..3)
  const int kh   = wave & 1;         // key half of the 64-key tile

  // XCD-bijective remap: flat = x + 16*y; xcd gets a contiguous 64-block chunk
  // = 4 bh x 16 q-blocks, so each bh's 512KB K/V is read within one L2.
  const int f    = blockIdx.x + 16 * blockIdx.y;
  const int i64  = f >> 3;
  const int bh   = (f & 7) * 4 + (i64 >> 4);
  const int q0   = (i64 & 15) * 128;
  const int bidx = bh >> 4, h = bh & 15;

  { // packed keep-masks for all 2048 keys (4 keys/thread)
    int4 m0 = *(const int4*)(mask + bidx * 2048 + tid * 4);
    uint2 dd;
    dd.x = (m0.x ? 0u : 0xFFFFu) | (m0.y ? 0u : 0xFFFF0000u);
    dd.y = (m0.z ? 0u : 0xFFFFu) | (m0.w ? 0u : 0xFFFF0000u);
    *(uint2*)(mask2 + tid * 2) = dd;
  }

  // Q fragments straight from global into registers (both kh waves of a qg
  // load the same rows -- duplicated, cheap)
  const u16* qg_ = qb + ((size_t)bh * 2048 + q0 + qg * 32) * 64;
  short8 qf[2][2];
#pragma unroll
  for (int kc = 0; kc < 2; ++kc)
#pragma unroll
    for (int nj = 0; nj < 2; ++nj)
      qf[kc][nj] = *(const short8*)(qg_ + (nj * 16 + c16) * 64 + kc * 32 + g4 * 8);

  const u16* kg = kb  + (size_t)bh * 2048 * 64;
  const u16* vg = vtb + (size_t)bh * 64 * 2048;
  { // stage K/V tile 0 into buffer 0: 512 threads, one 16B chunk each
    int r  = tid >> 3;
    int cp = (tid & 7) ^ (r & 7);
    gload16(kg + (size_t)r * 64 + cp * 8,   KsB + tid * 8);
    gload16(vg + (size_t)r * 2048 + cp * 8, VsB + tid * 8);
  }
  __syncthreads();

  short8 ones;
#pragma unroll
  for (int i = 0; i < 8; ++i) ones[i] = (short)0x3F80;   // bf16 1.0

  f32x4 O[2][4] = {};   // partial over this wave's key half
  f32x4 L[2] = {};

#pragma unroll 2
  for (int kt = 0; kt < 32; ++kt) {
    if (kt) __syncthreads();   // drains tile-kt loads + frees other buffer
    if (kt + 1 < 32) {
      const int nb = (kt + 1) & 1;
      int r  = tid >> 3;
      int cp = (tid & 7) ^ (r & 7);
      gload16(kg + (size_t)((kt + 1) * 64 + r) * 64 + cp * 8, KsB + nb * 4096 + tid * 8);
      gload16(vg + (size_t)r * 2048 + (kt + 1) * 64 + cp * 8, VsB + nb * 4096 + tid * 8);
    }
    const u16* ksb = KsB + (kt & 1) * 4096;
    const u16* vsb = VsB + (kt & 1) * 4096;

    // S^T[key 32 (this wave's half)][q 32]
    f32x4 S[2][2] = {};
    __builtin_amdgcn_s_setprio(1);
#pragma unroll
    for (int kc = 0; kc < 2; ++kc) {
      const int ch = ((kc * 4 + g4) ^ (c16 & 7)) * 8;
      short8 a[2];
#pragma unroll
      for (int mi = 0; mi < 2; ++mi)
        a[mi] = *(const short8*)(ksb + (kh * 32 + mi * 16 + c16) * 64 + ch);
#pragma unroll
      for (int mi = 0; mi < 2; ++mi)
#pragma unroll
        for (int nj = 0; nj < 2; ++nj)
          S[mi][nj] = __builtin_amdgcn_mfma_f32_16x16x32_bf16(a[mi], qf[kc][nj], S[mi][nj], 0, 0, 0);
    }
    __builtin_amdgcn_s_setprio(0);

    // keep-masks: reg r key = kh*32 + mi*16 + g4*4 + r
    uint2 mk[2];
#pragma unroll
    for (int mi = 0; mi < 2; ++mi)
      mk[mi] = *(const uint2*)(mask2 + kt * 32 + kh * 16 + mi * 8 + g4 * 2);

    // fixed-max softmax: P = exp2(S) & keep, packed to bf16, P -> LDS
    // (column half kh of Ps is wave-private: no barrier)
#pragma unroll
    for (int nj = 0; nj < 2; ++nj) {
      const int q = qg * 32 + nj * 16 + c16;
#pragma unroll
      for (int mi = 0; mi < 2; ++mi) {
        float p0 = __builtin_amdgcn_exp2f(S[mi][nj][0]);
        float p1 = __builtin_amdgcn_exp2f(S[mi][nj][1]);
        float p2 = __builtin_amdgcn_exp2f(S[mi][nj][2]);
        float p3 = __builtin_amdgcn_exp2f(S[mi][nj][3]);
        u32 lo = pkbf2(p0, p1) & mk[mi].x;
        u32 hi = pkbf2(p2, p3) & mk[mi].y;
        uint2 pkd; pkd.x = lo; pkd.y = hi;
        const int c = kh * 4 + mi * 2 + (g4 >> 1);
        *(uint2*)(Ps + q * 64 + ((c ^ (c16 & 7)) * 8 + (g4 & 1) * 4)) = pkd;
      }
    }

    // O[q 32][d 64] += P*V over this wave's 32 keys; L[q] += P*1
    {
      const int ch = ((kh * 4 + g4) ^ (c16 & 7)) * 8;
      short8 a2[2], b2[4];
#pragma unroll
      for (int mi = 0; mi < 2; ++mi)
        a2[mi] = *(const short8*)(Ps + (qg * 32 + mi * 16 + c16) * 64 + ch);
#pragma unroll
      for (int nd = 0; nd < 4; ++nd)
        b2[nd] = *(const short8*)(vsb + (nd * 16 + c16) * 64 + ch);
      __builtin_amdgcn_s_setprio(1);
#pragma unroll
      for (int mi = 0; mi < 2; ++mi) {
#pragma unroll
        for (int nd = 0; nd < 4; ++nd)
          O[mi][nd] = __builtin_amdgcn_mfma_f32_16x16x32_bf16(a2[mi], b2[nd], O[mi][nd], 0, 0, 0);
        L[mi] = __builtin_amdgcn_mfma_f32_16x16x32_bf16(a2[mi], ones, L[mi], 0, 0, 0);
      }
      __builtin_amdgcn_s_setprio(0);
    }
  }

  // epilogue: merge the two key-half partials (fixed-max => pure addition),
  // then O/L. Reduce buffer overlays the dead K/V/P LDS.
  __syncthreads();
  float* const redO = (float*)smem;            // [128][66] (+2 pad: 4-row bank spread)
  float* const redL = (float*)(smem + 33792);  // [128]
  if (kh) {
#pragma unroll
    for (int mi = 0; mi < 2; ++mi)
#pragma unroll
      for (int r = 0; r < 4; ++r) {
        int row = qg * 32 + mi * 16 + g4 * 4 + r;
#pragma unroll
        for (int nd = 0; nd < 4; ++nd)
          redO[row * 66 + nd * 16 + c16] = O[mi][nd][r];
        if (c16 == 0) redL[row] = L[mi][r];
      }
  }
  __syncthreads();
  if (!kh) {
    u16* og = ob + ((size_t)(bidx * 2048 + q0 + qg * 32)) * 1024 + h * 64;
#pragma unroll
    for (int mi = 0; mi < 2; ++mi)
#pragma unroll
      for (int r = 0; r < 4; ++r) {
        int row  = qg * 32 + mi * 16 + g4 * 4 + r;
        int qrow = mi * 16 + g4 * 4 + r;
        float linv = 1.f / (L[mi][r] + redL[row]);
#pragma unroll
        for (int nd = 0; nd < 4; ++nd) {
          float o = O[mi][nd][r] + redO[row * 66 + nd * 16 + c16];
          og[(size_t)qrow * 1024 + nd * 16 + c16] = f2bf(o * linv);
        }
      }
  }
}

// ---------------- k4: output projection, 128x64 tiles (2 blocks/CU) ----------------
__global__ __launch_bounds__(256) void gemm_out(const u16* __restrict__ A, const u16* __restrict__ Bt,
                         float* __restrict__ out) {
  __shared__ __align__(16) u16 As[128 * 64];
  __shared__ __align__(16) u16 Bs[64 * 64];
  const int tid  = threadIdx.x;
  const int wave = tid >> 6, lane = tid & 63;
  const int c16  = lane & 15, quad = lane >> 4;
  const int tile_m = blockIdx.x * 128;
  const int tile_n = blockIdx.y * 64;
  const int wm = wave * 32;
  const int sc   = lane & 7;

  f32x4 acc[4][2] = {};   // [feature blocks][token blocks]

  for (int k0 = 0; k0 < 1024; k0 += 64) {
    __syncthreads();
#pragma unroll
    for (int j = 0; j < 4; ++j) {      // A tile 128x64: 4 loads/thread
      int row = (tid >> 3) + j * 32;
      int cp  = sc ^ (row & 7);
      gload16(A + (size_t)(tile_m + row) * 1024 + k0 + cp * 8, As + row * 64 + sc * 8);
    }
#pragma unroll
    for (int j = 0; j < 2; ++j) {      // B tile 64x64: 2 loads/thread
      int row = (tid >> 3) + j * 32;
      int cp  = sc ^ (row & 7);
      gload16(Bt + (size_t)(tile_n + row) * 1024 + k0 + cp * 8, Bs + row * 64 + sc * 8);
    }
    __syncthreads();
#pragma unroll
    for (int kc = 0; kc < 2; ++kc) {
      const int ch = ((kc * 4 + quad) ^ (c16 & 7)) * 8;
      short8 fa[4], fb[2];
#pragma unroll
      for (int i = 0; i < 4; ++i)
        fa[i] = *(const short8*)(Bs + (i * 16 + c16) * 64 + ch);        // features
#pragma unroll
      for (int j = 0; j < 2; ++j)
        fb[j] = *(const short8*)(As + (wm + j * 16 + c16) * 64 + ch);   // tokens
#pragma unroll
      for (int i = 0; i < 4; ++i)
#pragma unroll
        for (int j = 0; j < 2; ++j)
          acc[i][j] = __builtin_amdgcn_mfma_f32_16x16x32_bf16(fa[i], fb[j], acc[i][j], 0, 0, 0);
    }
  }
#pragma unroll
  for (int i = 0; i < 4; ++i) {
    int f0 = tile_n + i * 16 + quad * 4;
#pragma unroll
    for (int j = 0; j < 2; ++j) {
      int t = tile_m + wm + j * 16 + c16;
      *(f32x4*)(out + (size_t)t * 1024 + f0) = acc[i][j];
    }
  }
}

extern "C" void kernel_launch(void* const* d_in, const int* in_sizes, int n_in,
                              void* d_out, int out_size, void* d_ws, size_t ws_size,
                              hipStream_t stream) {
  (void)in_sizes; (void)n_in; (void)out_size; (void)ws_size;
  const float* x    = (const float*)d_in[0];
  const int*   mask = (const int*)d_in[1];
  const float* wq   = (const float*)d_in[2];
  const float* wk   = (const float*)d_in[3];
  const float* wv   = (const float*)d_in[4];
  const float* wo   = (const float*)d_in[5];
  float* out = (float*)d_out;
  char*  ws  = (char*)d_ws;

  u16* xb   = (u16*)(ws + WS_XB);
  u16* wqkv = (u16*)(ws + WS_WQKV);
  u16* wob  = (u16*)(ws + WS_WOB);
  u16* qbuf = (u16*)(ws + WS_QB);
  u16* kbuf = (u16*)(ws + WS_KB);
  u16* vtb  = (u16*)(ws + WS_VTB);
  u16* obuf = (u16*)(ws + WS_OB);

  convert_k<<<2048, 256, 0, stream>>>(x, wq, wk, wv, wo, xb, wqkv, wob);
  gemm_qkv<<<dim3(32, 24), 256, 0, stream>>>(xb, wqkv, qbuf, kbuf, vtb);
  attn_k<<<dim3(16, 32), 512, 0, stream>>>(qbuf, kbuf, vtb, mask, obuf);
  gemm_out<<<dim3(32, 16), 256, 0, stream>>>(obuf, wob, out);
}